// Round 7
// baseline (2655.569 us; speedup 1.0000x reference)
//
#include <hip/hip_runtime.h>
#include <cstdint>
#include <cstddef>

#define T_LEN 1024
#define CH    1024
#define LAT   128
#define NBLK  128   // LSTM blocks; block b owns hidden dims [b*8, b*8+8)

// ---------------- ws layout (bytes) ----------------
// [0, 128 KiB)  : hbufP[2][1024][8]  tagged h broadcast, PADDED: one dim per
//                                    64B line (slot = (p*1024+d)*8 u64s).
//                                    u64 payload: tag<<32 | float_bits.
// [+16MiB+16K]  : hfin64[1024]       tagged final h (tag==1)
// [+16MiB+24K]  : cfin64[1024]       tagged final c (tag==1)
#define WS_HBUF  0
#define WS_HFIN  (16777216 + 16384)
#define WS_CFIN  (16777216 + 24576)

// LDS swizzle: logical float j stored at j ^ (((j>>4)&7)<<2).
// Read side: thread ln reads k = ln*16 + 4m; (k>>4)&7 == ln&7, so the
// physical 16B-slot index is ((4ln+m)&7) ^ (ln&7) — distinct across every
// 8 consecutive lanes for fixed m. Write side: b32 writes, bank = bijective
// xor of low 5 bits -> conflict-free. Bits 0-1 untouched -> float4 intact.
#define SWZ(j) ((j) ^ ((((j) >> 4) & 7) << 2))

// ---- fast gate math: v_exp_f32 (2^x) + v_rcp_f32 (round-3/5 validated) ----
#define LOG2E 1.44269504088896340736f
__device__ __forceinline__ float fsig(float x) {   // 1/(1+e^-x)
  return __builtin_amdgcn_rcpf(1.0f + __builtin_amdgcn_exp2f(-LOG2E * x));
}
__device__ __forceinline__ float ftanh(float x) {  // 1 - 2/(e^{2x}+1)
  float e = __builtin_amdgcn_exp2f(2.0f * LOG2E * x);
  return 1.0f - 2.0f * __builtin_amdgcn_rcpf(e + 1.0f);
}

__device__ __forceinline__ float dot4(float4 a, float4 b) {
  return a.x * b.x + a.y * b.y + a.z * b.z + a.w * b.w;
}

template <int CTRL, int RM>
__device__ __forceinline__ float dpp_add(float x) {
  int t = __builtin_amdgcn_update_dpp(0, __float_as_int(x), CTRL, RM, 0xf, true);
  return x + __int_as_float(t);
}

// 64-lane sum via DPP (VALU pipe only, no DS ops). Result valid in lane 63.
__device__ __forceinline__ float wave_sum63(float x) {
  x = dpp_add<0x111, 0xf>(x);   // row_shr:1
  x = dpp_add<0x112, 0xf>(x);   // row_shr:2
  x = dpp_add<0x114, 0xf>(x);   // row_shr:4
  x = dpp_add<0x118, 0xf>(x);   // row_shr:8  -> lane15 of each row = row sum
  x = dpp_add<0x142, 0xa>(x);   // row_bcast:15 -> rows 1,3
  x = dpp_add<0x143, 0xc>(x);   // row_bcast:31 -> rows 2,3; lane 63 = total
  return x;
}

__device__ __forceinline__ unsigned long long apoll(const unsigned long long* p) {
  return __hip_atomic_load(p, __ATOMIC_RELAXED, __HIP_MEMORY_SCOPE_AGENT);
}
__device__ __forceinline__ void apub(unsigned long long* p, unsigned tag, float v) {
  const unsigned long long pv =
      ((unsigned long long)tag << 32) | (unsigned long long)__float_as_uint(v);
  __hip_atomic_store(p, pv, __ATOMIC_RELAXED, __HIP_MEMORY_SCOPE_AGENT);
}

// ---------------- fused kernel: 128 blocks x 512 threads (8 waves) ----------------
// Round-5 structure verbatim (best measured: 2344us). Round-7 changes ONLY:
//  (1) exchange buffer PADDED to one dim per 64B line — removes the 8
//      publishers-per-line false sharing and spreads the consumer poll read
//      stream over 8x the L3 lines/banks;
//  (2) the two per-thread polls are INTERLEAVED (r5 serialized them:
//      word1's detection only started after word0 matched);
//  (3) no s_sleep (r6 measured: backoff adds latency; exchange is
//      latency-limited, not congestion-limited).
//
// Cross-block h exchange: fence-free tagged 64-bit relaxed agent-scope atomics.
// Payload = (tag<<32)|float_bits; tag t+1 published into slot parity (t+1)&1.
// D=2 slot reuse is race-free: publishing tag t+2 requires having consumed
// ALL tags t+1, which implies every block finished reading parity t&1.
__global__ __launch_bounds__(512, 2) void lstm_k(const int* __restrict__ tok,
                                                 const float* __restrict__ h0,
                                                 const float* __restrict__ c0,
                                                 const float* __restrict__ eps,
                                                 const float* __restrict__ emb,
                                                 const float* __restrict__ Wih,
                                                 const float* __restrict__ Whh,
                                                 const float* __restrict__ bih,
                                                 const float* __restrict__ bhh,
                                                 const float* __restrict__ Wm,
                                                 const float* __restrict__ bm,
                                                 const float* __restrict__ Wl,
                                                 const float* __restrict__ bl,
                                                 unsigned long long* __restrict__ hbufP,
                                                 unsigned long long* __restrict__ hfin64,
                                                 unsigned long long* __restrict__ cfin64,
                                                 float* __restrict__ out) {
  __shared__ float hs[2][1024];
  __shared__ float hcs[2048];
  __shared__ float rs[16];
  __shared__ int red[512];

  const int tid = threadIdx.x;
  const int b = blockIdx.x;
  const int wv = tid >> 6;            // wave 0..7 == dim within block
  const int ln = tid & 63;            // lane
  const int kbase = ln * 16;          // this thread's 16-float k-window
  const int swzm = (ln & 7) << 2;

  // ---- eos index (each block computes it redundantly) ----
  {
    int v0 = (tok[tid] == 1) ? tid : 0x7fffffff;
    int v1 = (tok[tid + 512] == 1) ? (tid + 512) : 0x7fffffff;
    red[tid] = min(v0, v1);
  }
  __syncthreads();
  for (int s = 256; s > 0; s >>= 1) {
    if (tid < s) red[tid] = min(red[tid], red[tid + s]);
    __syncthreads();
  }
  const int e0 = red[0];
  const int eos = (e0 == 0x7fffffff) ? 0 : e0;
  __syncthreads();

  // ---- weight fragments: rows q*1024 + b*8 + wv, k in [kbase, kbase+16) ----
  float4 wh[4][4];   // W_hh slice: 64 floats
  float4 wx[4][4];   // W_ih slice: 64 floats
#pragma unroll
  for (int q = 0; q < 4; q++) {
    const size_t roff = (size_t)(q * 1024 + b * 8 + wv) * CH + kbase;
#pragma unroll
    for (int m = 0; m < 4; m++) {
      wh[q][m] = *(const float4*)(Whh + roff + 4 * m);
      wx[q][m] = *(const float4*)(Wih + roff + 4 * m);
    }
  }

  // ---- lane-63 per-dim state: biases, h, c ----
  float bias0 = 0.f, bias1 = 0.f, bias2 = 0.f, bias3 = 0.f;
  float hreg = 0.f, creg = 0.f;
  if (ln == 63) {
    const int d = b * 8 + wv;
    bias0 = bih[d] + bhh[d];
    bias1 = bih[1024 + d] + bhh[1024 + d];
    bias2 = bih[2048 + d] + bhh[2048 + d];
    bias3 = bih[3072 + d] + bhh[3072 + d];
    hreg = h0[d];
    creg = c0[d];
  }

  for (int t = 0; t < eos; t++) {
    const int pb = t & 1;

    // ---- x-dot: independent of h, runs before/during the poll wait ----
    float a0, a1, a2, a3;
    {
      const float* xrow = emb + (size_t)tok[t] * CH + kbase;
      float4 xv0 = *(const float4*)(xrow);
      float4 xv1 = *(const float4*)(xrow + 4);
      float4 xv2 = *(const float4*)(xrow + 8);
      float4 xv3 = *(const float4*)(xrow + 12);
      a0 = dot4(wx[0][0], xv0) + dot4(wx[0][1], xv1) +
           dot4(wx[0][2], xv2) + dot4(wx[0][3], xv3);
      a1 = dot4(wx[1][0], xv0) + dot4(wx[1][1], xv1) +
           dot4(wx[1][2], xv2) + dot4(wx[1][3], xv3);
      a2 = dot4(wx[2][0], xv0) + dot4(wx[2][1], xv1) +
           dot4(wx[2][2], xv2) + dot4(wx[2][3], xv3);
      a3 = dot4(wx[3][0], xv0) + dot4(wx[3][1], xv1) +
           dot4(wx[3][2], xv2) + dot4(wx[3][3], xv3);
    }

    // ---- poll this thread's two h words (interleaved) into hs[pb] ----
    if (t == 0) {
      hs[0][SWZ(2 * tid)] = h0[2 * tid];
      hs[0][SWZ(2 * tid + 1)] = h0[2 * tid + 1];
    } else {
      const unsigned want = (unsigned)t;
      const unsigned long long* p0 = hbufP + ((size_t)pb * 1024 + 2 * tid) * 8;
      const unsigned long long* p1 = p0 + 8;   // next dim, next 64B line
      unsigned long long v0 = apoll(p0);
      unsigned long long v1 = apoll(p1);
      bool g0 = ((unsigned)(v0 >> 32) == want);
      bool g1 = ((unsigned)(v1 >> 32) == want);
      while (!(g0 && g1)) {
        if (!g0) { v0 = apoll(p0); g0 = ((unsigned)(v0 >> 32) == want); }
        if (!g1) { v1 = apoll(p1); g1 = ((unsigned)(v1 >> 32) == want); }
      }
      hs[pb][SWZ(2 * tid)] = __uint_as_float((unsigned)(v0 & 0xffffffffu));
      hs[pb][SWZ(2 * tid + 1)] = __uint_as_float((unsigned)(v1 & 0xffffffffu));
    }
    __syncthreads();   // the only barrier in the step

    // ---- h-dot: wave wv's dim, conflict-free swizzled b128 reads ----
#pragma unroll
    for (int m = 0; m < 4; m++) {
      const float4 h4 = *(const float4*)&hs[pb][(kbase + 4 * m) ^ swzm];
      a0 += dot4(wh[0][m], h4);
      a1 += dot4(wh[1][m], h4);
      a2 += dot4(wh[2][m], h4);
      a3 += dot4(wh[3][m], h4);
    }
    a0 = wave_sum63(a0);
    a1 = wave_sum63(a1);
    a2 = wave_sum63(a2);
    a3 = wave_sum63(a3);

    if (ln == 63) {
      const float iv = a0 + bias0, fv = a1 + bias1;
      const float gg = a2 + bias2, ov = a3 + bias3;
      const float cn = fsig(fv) * creg + fsig(iv) * ftanh(gg);
      const float hn = fsig(ov) * ftanh(cn);
      creg = cn; hreg = hn;
      apub(hbufP + ((size_t)((t + 1) & 1) * 1024 + b * 8 + wv) * 8,
           (unsigned)(t + 1), hn);
    }
  }

  // publish final h, c (tag == 1; workspace poison never matches)
  if (ln == 63) {
    apub(&hfin64[b * 8 + wv], 1u, hreg);
    apub(&cfin64[b * 8 + wv], 1u, creg);
  }

  // gather full hc = concat(h, c): each thread polls 2 h words + 2 c words
  {
#pragma unroll
    for (int part = 0; part < 2; part++) {
      const int i = tid + part * 512;
      unsigned long long vh, vc;
      do { vh = apoll(&hfin64[i]); } while ((unsigned)(vh >> 32) != 1u);
      do { vc = apoll(&cfin64[i]); } while ((unsigned)(vc >> 32) != 1u);
      hcs[i] = __uint_as_float((unsigned)(vh & 0xffffffffu));
      hcs[1024 + i] = __uint_as_float((unsigned)(vc & 0xffffffffu));
    }
  }
  __syncthreads();

  // projections: block b computes mean[b], logv[b] (2048-dot each)
  float pm = 0.f, pl = 0.f;
#pragma unroll
  for (int part = 0; part < 4; part++) {
    const int j = tid + part * 512;
    const float hcv = hcs[j];
    pm += Wm[(size_t)b * 2048 + j] * hcv;
    pl += Wl[(size_t)b * 2048 + j] * hcv;
  }
#pragma unroll
  for (int o = 32; o > 0; o >>= 1) {
    pm += __shfl_down(pm, o);
    pl += __shfl_down(pl, o);
  }
  if (ln == 0) { rs[wv] = pm; rs[8 + wv] = pl; }
  __syncthreads();
  if (tid == 0) {
    float m = 0.0f, l = 0.0f;
    for (int i = 0; i < 8; i++) { m += rs[i]; l += rs[8 + i]; }
    m += bm[b];
    l += bl[b];
    const float z = eps[b] * expf(0.5f * l) + m;
    out[b] = z;
    out[LAT + b] = m;
    out[2 * LAT + b] = l;
  }
}

extern "C" void kernel_launch(void* const* d_in, const int* in_sizes, int n_in,
                              void* d_out, int out_size, void* d_ws, size_t ws_size,
                              hipStream_t stream) {
  const int*   tok = (const int*)d_in[0];
  const float* h0  = (const float*)d_in[1];
  const float* c0  = (const float*)d_in[2];
  const float* eps = (const float*)d_in[3];
  const float* emb = (const float*)d_in[4];
  const float* Wih = (const float*)d_in[5];
  const float* Whh = (const float*)d_in[6];
  const float* bih = (const float*)d_in[7];
  const float* bhh = (const float*)d_in[8];
  const float* Wm  = (const float*)d_in[9];
  const float* bm  = (const float*)d_in[10];
  const float* Wl  = (const float*)d_in[11];
  const float* bl  = (const float*)d_in[12];
  float* out = (float*)d_out;

  char* ws = (char*)d_ws;
  unsigned long long* hbufP  = (unsigned long long*)(ws + WS_HBUF);
  unsigned long long* hfin64 = (unsigned long long*)(ws + WS_HFIN);
  unsigned long long* cfin64 = (unsigned long long*)(ws + WS_CFIN);

  lstm_k<<<dim3(NBLK), dim3(512), 0, stream>>>(
      tok, h0, c0, eps, emb, Wih, Whh, bih, bhh, Wm, bm, Wl, bl,
      hbufP, hfin64, cfin64, out);
}

// Round 8
// 2286.562 us; speedup vs baseline: 1.1614x; 1.1614x over previous
//
#include <hip/hip_runtime.h>
#include <cstdint>
#include <cstddef>

#define T_LEN 1024
#define CH    1024
#define LAT   128
#define NBLK  128   // LSTM blocks; block b owns hidden dims [b*8, b*8+8)

// ---------------- ws layout (bytes) ----------------
// [+16 MiB]     : hbuf64[2][1024]    tagged h broadcast (u64: tag<<32 | bits)
// [+16MiB+16K]  : hfin64[1024]       tagged final h (tag==1)
// [+16MiB+24K]  : cfin64[1024]       tagged final c (tag==1)
#define WS_HBUF  (16777216)
#define WS_HFIN  (16777216 + 16384)
#define WS_CFIN  (16777216 + 24576)

// LDS swizzle: logical float j stored at j ^ (((j>>4)&7)<<2).
// Read side: thread ln reads k = ln*16 + 4m; (k>>4)&7 == ln&7, so the
// physical 16B-slot index is ((4ln+m)&7) ^ (ln&7) — distinct across every
// 8 consecutive lanes for fixed m. Write side: b32 writes, bank = bijective
// xor of low 5 bits -> conflict-free. Bits 0-1 untouched -> float4 intact.
#define SWZ(j) ((j) ^ ((((j) >> 4) & 7) << 2))

// ---- fast gate math: v_exp_f32 (2^x) + v_rcp_f32 (round-3/5 validated) ----
#define LOG2E 1.44269504088896340736f
__device__ __forceinline__ float fsig(float x) {   // 1/(1+e^-x)
  return __builtin_amdgcn_rcpf(1.0f + __builtin_amdgcn_exp2f(-LOG2E * x));
}
__device__ __forceinline__ float ftanh(float x) {  // 1 - 2/(e^{2x}+1)
  float e = __builtin_amdgcn_exp2f(2.0f * LOG2E * x);
  return 1.0f - 2.0f * __builtin_amdgcn_rcpf(e + 1.0f);
}

__device__ __forceinline__ float dot4(float4 a, float4 b) {
  return a.x * b.x + a.y * b.y + a.z * b.z + a.w * b.w;
}

template <int CTRL, int RM>
__device__ __forceinline__ float dpp_add(float x) {
  int t = __builtin_amdgcn_update_dpp(0, __float_as_int(x), CTRL, RM, 0xf, true);
  return x + __int_as_float(t);
}

// 64-lane sum via DPP (VALU pipe only, no DS ops). Result valid in lane 63.
__device__ __forceinline__ float wave_sum63(float x) {
  x = dpp_add<0x111, 0xf>(x);   // row_shr:1
  x = dpp_add<0x112, 0xf>(x);   // row_shr:2
  x = dpp_add<0x114, 0xf>(x);   // row_shr:4
  x = dpp_add<0x118, 0xf>(x);   // row_shr:8  -> lane15 of each row = row sum
  x = dpp_add<0x142, 0xa>(x);   // row_bcast:15 -> rows 1,3
  x = dpp_add<0x143, 0xc>(x);   // row_bcast:31 -> rows 2,3; lane 63 = total
  return x;
}

__device__ __forceinline__ unsigned long long apoll(const unsigned long long* p) {
  return __hip_atomic_load(p, __ATOMIC_RELAXED, __HIP_MEMORY_SCOPE_AGENT);
}
__device__ __forceinline__ void apub(unsigned long long* p, unsigned tag, float v) {
  const unsigned long long pv =
      ((unsigned long long)tag << 32) | (unsigned long long)__float_as_uint(v);
  __hip_atomic_store(p, pv, __ATOMIC_RELAXED, __HIP_MEMORY_SCOPE_AGENT);
}

// ---------------- fused kernel: 128 blocks x 512 threads (8 waves) ----------------
// Round-5 structure verbatim (best measured: 2344us total / 2104us kernel).
// ONLY change vs r5: the two per-thread polls are INTERLEAVED (r5 serialized
// them — word1's detection only started after word0 matched). Buffer is the
// UNPADDED r5 layout (r7 measured: line padding inflates fabric bytes 4.5x
// and costs +345us). No s_sleep (r6: backoff adds latency; the exchange is
// latency-limited, not congestion-limited).
//
// Wave d owns dim b*8+d completely; DPP reduce lands i,f,g,o in lane 63,
// which applies gates and publishes immediately. One barrier/step;
// hs[2][1024] double-buffered.
//
// Cross-block h exchange: fence-free tagged 64-bit relaxed agent-scope atomics.
// Payload = (tag<<32)|float_bits; tag t+1 published into slot (t+1)&1.
// D=2 slot reuse is race-free: publishing tag t+2 requires having consumed
// ALL tags t+1, which implies every block finished reading slot t&1.
__global__ __launch_bounds__(512, 2) void lstm_k(const int* __restrict__ tok,
                                                 const float* __restrict__ h0,
                                                 const float* __restrict__ c0,
                                                 const float* __restrict__ eps,
                                                 const float* __restrict__ emb,
                                                 const float* __restrict__ Wih,
                                                 const float* __restrict__ Whh,
                                                 const float* __restrict__ bih,
                                                 const float* __restrict__ bhh,
                                                 const float* __restrict__ Wm,
                                                 const float* __restrict__ bm,
                                                 const float* __restrict__ Wl,
                                                 const float* __restrict__ bl,
                                                 unsigned long long* __restrict__ hbuf64,
                                                 unsigned long long* __restrict__ hfin64,
                                                 unsigned long long* __restrict__ cfin64,
                                                 float* __restrict__ out) {
  __shared__ float hs[2][1024];
  __shared__ float hcs[2048];
  __shared__ float rs[16];
  __shared__ int red[512];

  const int tid = threadIdx.x;
  const int b = blockIdx.x;
  const int wv = tid >> 6;            // wave 0..7 == dim within block
  const int ln = tid & 63;            // lane
  const int kbase = ln * 16;          // this thread's 16-float k-window
  const int swzm = (ln & 7) << 2;

  // ---- eos index (each block computes it redundantly) ----
  {
    int v0 = (tok[tid] == 1) ? tid : 0x7fffffff;
    int v1 = (tok[tid + 512] == 1) ? (tid + 512) : 0x7fffffff;
    red[tid] = min(v0, v1);
  }
  __syncthreads();
  for (int s = 256; s > 0; s >>= 1) {
    if (tid < s) red[tid] = min(red[tid], red[tid + s]);
    __syncthreads();
  }
  const int e0 = red[0];
  const int eos = (e0 == 0x7fffffff) ? 0 : e0;
  __syncthreads();

  // ---- weight fragments: rows q*1024 + b*8 + wv, k in [kbase, kbase+16) ----
  float4 wh[4][4];   // W_hh slice: 64 floats
  float4 wx[4][4];   // W_ih slice: 64 floats
#pragma unroll
  for (int q = 0; q < 4; q++) {
    const size_t roff = (size_t)(q * 1024 + b * 8 + wv) * CH + kbase;
#pragma unroll
    for (int m = 0; m < 4; m++) {
      wh[q][m] = *(const float4*)(Whh + roff + 4 * m);
      wx[q][m] = *(const float4*)(Wih + roff + 4 * m);
    }
  }

  // ---- lane-63 per-dim state: biases, h, c ----
  float bias0 = 0.f, bias1 = 0.f, bias2 = 0.f, bias3 = 0.f;
  float hreg = 0.f, creg = 0.f;
  if (ln == 63) {
    const int d = b * 8 + wv;
    bias0 = bih[d] + bhh[d];
    bias1 = bih[1024 + d] + bhh[1024 + d];
    bias2 = bih[2048 + d] + bhh[2048 + d];
    bias3 = bih[3072 + d] + bhh[3072 + d];
    hreg = h0[d];
    creg = c0[d];
  }

  for (int t = 0; t < eos; t++) {
    const int pb = t & 1;

    // ---- x-dot: independent of h, runs before/during the poll wait ----
    float a0, a1, a2, a3;
    {
      const float* xrow = emb + (size_t)tok[t] * CH + kbase;
      float4 xv0 = *(const float4*)(xrow);
      float4 xv1 = *(const float4*)(xrow + 4);
      float4 xv2 = *(const float4*)(xrow + 8);
      float4 xv3 = *(const float4*)(xrow + 12);
      a0 = dot4(wx[0][0], xv0) + dot4(wx[0][1], xv1) +
           dot4(wx[0][2], xv2) + dot4(wx[0][3], xv3);
      a1 = dot4(wx[1][0], xv0) + dot4(wx[1][1], xv1) +
           dot4(wx[1][2], xv2) + dot4(wx[1][3], xv3);
      a2 = dot4(wx[2][0], xv0) + dot4(wx[2][1], xv1) +
           dot4(wx[2][2], xv2) + dot4(wx[2][3], xv3);
      a3 = dot4(wx[3][0], xv0) + dot4(wx[3][1], xv1) +
           dot4(wx[3][2], xv2) + dot4(wx[3][3], xv3);
    }

    // ---- poll this thread's two h words (interleaved) into hs[pb] ----
    if (t == 0) {
      hs[0][SWZ(2 * tid)] = h0[2 * tid];
      hs[0][SWZ(2 * tid + 1)] = h0[2 * tid + 1];
    } else {
      const unsigned want = (unsigned)t;
      const unsigned long long* src = hbuf64 + (size_t)pb * 1024 + 2 * tid;
      unsigned long long v0 = apoll(src);
      unsigned long long v1 = apoll(src + 1);
      bool g0 = ((unsigned)(v0 >> 32) == want);
      bool g1 = ((unsigned)(v1 >> 32) == want);
      while (!(g0 && g1)) {
        if (!g0) { v0 = apoll(src); g0 = ((unsigned)(v0 >> 32) == want); }
        if (!g1) { v1 = apoll(src + 1); g1 = ((unsigned)(v1 >> 32) == want); }
      }
      hs[pb][SWZ(2 * tid)] = __uint_as_float((unsigned)(v0 & 0xffffffffu));
      hs[pb][SWZ(2 * tid + 1)] = __uint_as_float((unsigned)(v1 & 0xffffffffu));
    }
    __syncthreads();   // the only barrier in the step

    // ---- h-dot: wave wv's dim, conflict-free swizzled b128 reads ----
#pragma unroll
    for (int m = 0; m < 4; m++) {
      const float4 h4 = *(const float4*)&hs[pb][(kbase + 4 * m) ^ swzm];
      a0 += dot4(wh[0][m], h4);
      a1 += dot4(wh[1][m], h4);
      a2 += dot4(wh[2][m], h4);
      a3 += dot4(wh[3][m], h4);
    }
    a0 = wave_sum63(a0);
    a1 = wave_sum63(a1);
    a2 = wave_sum63(a2);
    a3 = wave_sum63(a3);

    if (ln == 63) {
      const float iv = a0 + bias0, fv = a1 + bias1;
      const float gg = a2 + bias2, ov = a3 + bias3;
      const float cn = fsig(fv) * creg + fsig(iv) * ftanh(gg);
      const float hn = fsig(ov) * ftanh(cn);
      creg = cn; hreg = hn;
      apub(&hbuf64[(size_t)((t + 1) & 1) * 1024 + b * 8 + wv],
           (unsigned)(t + 1), hn);
    }
  }

  // publish final h, c (tag == 1; workspace poison never matches)
  if (ln == 63) {
    apub(&hfin64[b * 8 + wv], 1u, hreg);
    apub(&cfin64[b * 8 + wv], 1u, creg);
  }

  // gather full hc = concat(h, c): each thread polls 2 h words + 2 c words
  {
#pragma unroll
    for (int part = 0; part < 2; part++) {
      const int i = tid + part * 512;
      unsigned long long vh, vc;
      do { vh = apoll(&hfin64[i]); } while ((unsigned)(vh >> 32) != 1u);
      do { vc = apoll(&cfin64[i]); } while ((unsigned)(vc >> 32) != 1u);
      hcs[i] = __uint_as_float((unsigned)(vh & 0xffffffffu));
      hcs[1024 + i] = __uint_as_float((unsigned)(vc & 0xffffffffu));
    }
  }
  __syncthreads();

  // projections: block b computes mean[b], logv[b] (2048-dot each)
  float pm = 0.f, pl = 0.f;
#pragma unroll
  for (int part = 0; part < 4; part++) {
    const int j = tid + part * 512;
    const float hcv = hcs[j];
    pm += Wm[(size_t)b * 2048 + j] * hcv;
    pl += Wl[(size_t)b * 2048 + j] * hcv;
  }
#pragma unroll
  for (int o = 32; o > 0; o >>= 1) {
    pm += __shfl_down(pm, o);
    pl += __shfl_down(pl, o);
  }
  if (ln == 0) { rs[wv] = pm; rs[8 + wv] = pl; }
  __syncthreads();
  if (tid == 0) {
    float m = 0.0f, l = 0.0f;
    for (int i = 0; i < 8; i++) { m += rs[i]; l += rs[8 + i]; }
    m += bm[b];
    l += bl[b];
    const float z = eps[b] * expf(0.5f * l) + m;
    out[b] = z;
    out[LAT + b] = m;
    out[2 * LAT + b] = l;
  }
}

extern "C" void kernel_launch(void* const* d_in, const int* in_sizes, int n_in,
                              void* d_out, int out_size, void* d_ws, size_t ws_size,
                              hipStream_t stream) {
  const int*   tok = (const int*)d_in[0];
  const float* h0  = (const float*)d_in[1];
  const float* c0  = (const float*)d_in[2];
  const float* eps = (const float*)d_in[3];
  const float* emb = (const float*)d_in[4];
  const float* Wih = (const float*)d_in[5];
  const float* Whh = (const float*)d_in[6];
  const float* bih = (const float*)d_in[7];
  const float* bhh = (const float*)d_in[8];
  const float* Wm  = (const float*)d_in[9];
  const float* bm  = (const float*)d_in[10];
  const float* Wl  = (const float*)d_in[11];
  const float* bl  = (const float*)d_in[12];
  float* out = (float*)d_out;

  char* ws = (char*)d_ws;
  unsigned long long* hbuf64 = (unsigned long long*)(ws + WS_HBUF);
  unsigned long long* hfin64 = (unsigned long long*)(ws + WS_HFIN);
  unsigned long long* cfin64 = (unsigned long long*)(ws + WS_CFIN);

  lstm_k<<<dim3(NBLK), dim3(512), 0, stream>>>(
      tok, h0, c0, eps, emb, Wih, Whh, bih, bhh, Wm, bm, Wl, bl,
      hbuf64, hfin64, cfin64, out);
}